// Round 7
// baseline (139.703 us; speedup 1.0000x reference)
//
#include <hip/hip_runtime.h>

#define M_DIM 512
#define N_DIM 4096
#define K_DIM 4096

typedef __attribute__((ext_vector_type(16))) float f32x16;

// ---- ws layout (bytes) ----
// [0,1024)      float part_x[256]
// [1024,5120)   float part_w[1024]
// [5120,5128)   float amax_final[2]
// [8192, +2MB)  xq fp8
// [then, +16MB) wq fp8
#define PART_X_OFF 0
#define PART_X_N   256
#define PART_W_OFF 256
#define PART_W_N   1024
#define AMAX_OFF   1280
#define XQ_BYTE_OFF 8192
#define WQ_BYTE_OFF (XQ_BYTE_OFF + M_DIM * K_DIM)

// ---------------------------------------------------------------- amax ------
__global__ __launch_bounds__(256) void amax_kernel(
    const float4* __restrict__ x4, const float4* __restrict__ w4,
    float* __restrict__ ws_f) {
    const int b = blockIdx.x;
    float m = 0.0f;
    if (b < PART_X_N) {  // x: 256 blocks
        const int n4 = M_DIM * K_DIM / 4, stride = PART_X_N * 256;
        for (int i = b * 256 + threadIdx.x; i < n4; i += stride) {
            float4 a = x4[i];
            m = fmaxf(m, fmaxf(fmaxf(fabsf(a.x), fabsf(a.y)),
                               fmaxf(fabsf(a.z), fabsf(a.w))));
        }
    } else {             // w: 1024 blocks
        const int n4 = N_DIM * K_DIM / 4, stride = PART_W_N * 256;
        for (int i = (b - PART_X_N) * 256 + threadIdx.x; i < n4; i += stride) {
            float4 a = w4[i];
            m = fmaxf(m, fmaxf(fmaxf(fabsf(a.x), fabsf(a.y)),
                               fmaxf(fabsf(a.z), fabsf(a.w))));
        }
    }
    for (int off = 32; off > 0; off >>= 1)
        m = fmaxf(m, __shfl_down(m, off, 64));
    __shared__ float sm[4];
    if ((threadIdx.x & 63) == 0) sm[threadIdx.x >> 6] = m;
    __syncthreads();
    if (threadIdx.x == 0) {
        m = fmaxf(fmaxf(sm[0], sm[1]), fmaxf(sm[2], sm[3]));
        ws_f[(b < PART_X_N) ? (PART_X_OFF + b) : (PART_W_OFF + b - PART_X_N)] = m;
    }
}

// ------------------------------------------------------------- quantize -----
// e2m1 codebook values as OCP e4m3fn bytes (exact): 0,0.5,1,1.5,2,3,4,6.
// Midpoint ties -> smaller magnitude (matches jnp.argmin first-occurrence).
__device__ __forceinline__ unsigned int q1(float x, float s) {
    float a = fabsf(x) * s;
    unsigned int b;
    if      (a <= 0.25f) b = 0x00u;  // 0.0
    else if (a <= 0.75f) b = 0x30u;  // 0.5
    else if (a <= 1.25f) b = 0x38u;  // 1.0
    else if (a <= 1.75f) b = 0x3Cu;  // 1.5
    else if (a <= 2.5f)  b = 0x40u;  // 2.0
    else if (a <= 3.5f)  b = 0x44u;  // 3.0
    else if (a <= 5.0f)  b = 0x48u;  // 4.0
    else                 b = 0x4Cu;  // 6.0 (also handles clip)
    return b | ((__float_as_uint(x) >> 24) & 0x80u);
}
__device__ __forceinline__ unsigned int qpack4(float4 v, float s) {
    return q1(v.x, s) | (q1(v.y, s) << 8) | (q1(v.z, s) << 16) | (q1(v.w, s) << 24);
}

__global__ __launch_bounds__(256) void quant_kernel(
    const float4* __restrict__ x4, const float4* __restrict__ w4,
    float* __restrict__ ws_f, unsigned char* __restrict__ ws_b) {
    const int b = blockIdx.x, t = threadIdx.x;
    const bool is_x = b < 512;
    float m = 0.0f;
    if (is_x) {
        m = ws_f[PART_X_OFF + t];
    } else {
        for (int i = t; i < PART_W_N; i += 256)
            m = fmaxf(m, ws_f[PART_W_OFF + i]);
    }
    for (int off = 32; off > 0; off >>= 1)
        m = fmaxf(m, __shfl_down(m, off, 64));
    __shared__ float sm[4];
    if ((t & 63) == 0) sm[t >> 6] = m;
    __syncthreads();
    m = fmaxf(fmaxf(sm[0], sm[1]), fmaxf(sm[2], sm[3]));
    float amax = fmaxf(m, 1e-12f);
    float s = 6.0f / amax;
    if (t == 0 && b == 0)   ws_f[AMAX_OFF + 0] = amax;
    if (t == 0 && b == 512) ws_f[AMAX_OFF + 1] = amax;

    const float4* src = is_x ? x4 : w4;
    unsigned char* dstb = ws_b + (is_x ? XQ_BYTE_OFF : WQ_BYTE_OFF);
    const int idx16 = (is_x ? b : b - 512) * 256 + t;
    const float4* p = src + (size_t)idx16 * 4;
    uint4 o;
    o.x = qpack4(p[0], s);
    o.y = qpack4(p[1], s);
    o.z = qpack4(p[2], s);
    o.w = qpack4(p[3], s);
    ((uint4*)dstb)[idx16] = o;
}

// ----------------------------------------------------------------- GEMM -----
__device__ __forceinline__ void async_copy16(const void* g, void* l) {
    __builtin_amdgcn_global_load_lds(
        (const __attribute__((address_space(1))) unsigned int*)g,
        (__attribute__((address_space(3))) unsigned int*)l, 16, 0, 0);
}

// C[m,n] = sum_k A[m,k]*B[n,k], fp8 operands (codebook units), full K per
// block, plain stores. 64x64 tile -> 512 blocks (2/CU), BK=512 (8 barrier
// drains). NEW vs R6: waves pair-split K — waves (0,2) own rows 0-31,
// (1,3) rows 32-63; each wave computes a 32x64 tile over half of K via
// v_mfma_f32_32x32x16_fp8_fp8 (2 acc[16]; 3 b64 reads + 2 MFMAs per K=16
// = 25% less LDS read traffic than the 2x2 16x16 form). In-LDS pair-sum
// epilogue (16 KB scratch in As, one barrier, all waves alive).
__global__ __launch_bounds__(256, 2) void gemm_kernel(
    const unsigned char* __restrict__ A, const unsigned char* __restrict__ B,
    float* __restrict__ C, const float* __restrict__ amax2) {
    __shared__ __align__(16) unsigned char As[64 * 512];
    __shared__ __align__(16) unsigned char Bs[64 * 512];

    const int bid  = blockIdx.x;
    // bid = mt*64 + g*8 + x : x = XCD slice (N), g = n-subtile, mt = m-tile
    const int bm   = (bid >> 6) * 64;
    const int bn   = ((bid & 7) * 8 + ((bid >> 3) & 7)) * 64;
    const int tid  = threadIdx.x;
    const int lane = tid & 63;
    const int wave = tid >> 6;
    const int pr   = wave & 1;   // row-pair: rows pr*32..pr*32+31
    const int kh   = wave >> 1;  // K-half within each 512-stage
    const int l31  = lane & 31;
    const int koff = (lane >> 5) * 8;  // k-byte subgroup within 16B chunk

    const float cs = (1.0f / (6.0f / fmaxf(amax2[0], 1e-12f))) *
                     (1.0f / (6.0f / fmaxf(amax2[1], 1e-12f)));

    // staging: chunk c = j*256 + tid, LDS byte c*16 (wave-uniform base +
    // lane*16). Physical slot (row=c>>5, pcol=c&31) holds global 16B-chunk
    // gk = pcol ^ (row&31) of that row.
    const unsigned char* agp[8];
    const unsigned char* bgp[8];
#pragma unroll
    for (int j = 0; j < 8; j++) {
        const int c = j * 256 + tid;
        const int row = c >> 5, pcol = c & 31;
        const int gk = pcol ^ (row & 31);
        agp[j] = A + (size_t)(bm + row) * K_DIM + gk * 16;
        bgp[j] = B + (size_t)(bn + row) * K_DIM + gk * 16;
    }

    f32x16 acc[2] = {};
    // frag row bases (row & 31 == l31 for all three -> shared swizzle)
    const unsigned char* arow = As + (pr * 32 + l31) * 512;
    const unsigned char* brow0 = Bs + l31 * 512;
    const unsigned char* brow1 = Bs + (32 + l31) * 512;

    for (int ko = 0; ko < K_DIM; ko += 512) {
#pragma unroll
        for (int j = 0; j < 8; j++) {
            async_copy16(agp[j] + ko, As + (j * 256 + tid) * 16);
            async_copy16(bgp[j] + ko, Bs + (j * 256 + tid) * 16);
        }
        __syncthreads();

#pragma unroll
        for (int s = 0; s < 16; s++) {
            const int g = kh * 16 + s;                     // 16B chunk index
            const int off = ((g ^ l31) * 16) + koff;       // swizzled byte
            const long a0 = *(const long*)(arow + off);
            const long b0 = *(const long*)(brow0 + off);
            const long b1 = *(const long*)(brow1 + off);
            acc[0] = __builtin_amdgcn_mfma_f32_32x32x16_fp8_fp8(a0, b0, acc[0], 0, 0, 0);
            acc[1] = __builtin_amdgcn_mfma_f32_32x32x16_fp8_fp8(a0, b1, acc[1], 0, 0, 0);
        }
        __syncthreads();
    }

    // ---- pair-sum epilogue ----
    // 32x32 C/D layout: col = lane&31, row = (reg&3) + 8*(reg>>2) + 4*(lane>>5)
    float* scratch = (float*)As;  // 16 KB used (pair pr region = 8 KB)
    if (kh == 1) {
#pragma unroll
        for (int j = 0; j < 2; j++)
#pragma unroll
            for (int r = 0; r < 16; r++) {
                const int rl = (r & 3) + 8 * (r >> 2) + 4 * (lane >> 5);
                scratch[pr * 2048 + rl * 64 + j * 32 + l31] = acc[j][r];
            }
    }
    __syncthreads();
    if (kh == 0) {
#pragma unroll
        for (int j = 0; j < 2; j++)
#pragma unroll
            for (int r = 0; r < 16; r++) {
                const int rl = (r & 3) + 8 * (r >> 2) + 4 * (lane >> 5);
                const float v = (acc[j][r] +
                                 scratch[pr * 2048 + rl * 64 + j * 32 + l31]) * cs;
                C[(size_t)(bm + pr * 32 + rl) * N_DIM + bn + j * 32 + l31] = v;
            }
    }
}

// ---------------------------------------------------------------- launch ----
extern "C" void kernel_launch(void* const* d_in, const int* in_sizes, int n_in,
                              void* d_out, int out_size, void* d_ws, size_t ws_size,
                              hipStream_t stream) {
    const float* x = (const float*)d_in[0];   // [512, 4096]
    const float* w = (const float*)d_in[1];   // [4096, 4096]
    float* out = (float*)d_out;               // [512, 4096]

    float* ws_f = (float*)d_ws;
    unsigned char* ws_b = (unsigned char*)d_ws;
    const unsigned char* xq = ws_b + XQ_BYTE_OFF;
    const unsigned char* wq = ws_b + WQ_BYTE_OFF;

    amax_kernel<<<PART_X_N + PART_W_N, 256, 0, stream>>>(
        (const float4*)x, (const float4*)w, ws_f);
    quant_kernel<<<512 + 4096, 256, 0, stream>>>(
        (const float4*)x, (const float4*)w, ws_f, ws_b);
    gemm_kernel<<<(M_DIM / 64) * (N_DIM / 64), 256, 0, stream>>>(
        xq, wq, out, ws_f + AMAX_OFF);
}

// Round 8
// 134.359 us; speedup vs baseline: 1.0398x; 1.0398x over previous
//
#include <hip/hip_runtime.h>

#define M_DIM 512
#define N_DIM 4096
#define K_DIM 4096

typedef __attribute__((ext_vector_type(4))) float f32x4;
typedef __attribute__((ext_vector_type(8))) int i32x8;
typedef __attribute__((ext_vector_type(4))) int i32x4;

// ---- ws layout (bytes) ----
// [0,1024)      float part_x[256]
// [1024,5120)   float part_w[1024]
// [5120,5128)   float amax_final[2]
// [8192, +2MB)  xq fp8
// [then, +16MB) wq fp8
#define PART_X_OFF 0
#define PART_X_N   256
#define PART_W_OFF 256
#define PART_W_N   1024
#define AMAX_OFF   1280
#define XQ_BYTE_OFF 8192
#define WQ_BYTE_OFF (XQ_BYTE_OFF + M_DIM * K_DIM)

// ---------------------------------------------------------------- amax ------
__global__ __launch_bounds__(256) void amax_kernel(
    const float4* __restrict__ x4, const float4* __restrict__ w4,
    float* __restrict__ ws_f) {
    const int b = blockIdx.x;
    float m = 0.0f;
    if (b < PART_X_N) {  // x: 256 blocks
        const int n4 = M_DIM * K_DIM / 4, stride = PART_X_N * 256;
        for (int i = b * 256 + threadIdx.x; i < n4; i += stride) {
            float4 a = x4[i];
            m = fmaxf(m, fmaxf(fmaxf(fabsf(a.x), fabsf(a.y)),
                               fmaxf(fabsf(a.z), fabsf(a.w))));
        }
    } else {             // w: 1024 blocks
        const int n4 = N_DIM * K_DIM / 4, stride = PART_W_N * 256;
        for (int i = (b - PART_X_N) * 256 + threadIdx.x; i < n4; i += stride) {
            float4 a = w4[i];
            m = fmaxf(m, fmaxf(fmaxf(fabsf(a.x), fabsf(a.y)),
                               fmaxf(fabsf(a.z), fabsf(a.w))));
        }
    }
    for (int off = 32; off > 0; off >>= 1)
        m = fmaxf(m, __shfl_down(m, off, 64));
    __shared__ float sm[4];
    if ((threadIdx.x & 63) == 0) sm[threadIdx.x >> 6] = m;
    __syncthreads();
    if (threadIdx.x == 0) {
        m = fmaxf(fmaxf(sm[0], sm[1]), fmaxf(sm[2], sm[3]));
        ws_f[(b < PART_X_N) ? (PART_X_OFF + b) : (PART_W_OFF + b - PART_X_N)] = m;
    }
}

// ------------------------------------------------------------- quantize -----
// e2m1 codebook values as OCP e4m3fn bytes (exact): 0,0.5,1,1.5,2,3,4,6.
// Midpoint ties -> smaller magnitude (matches jnp.argmin first-occurrence).
__device__ __forceinline__ unsigned int q1(float x, float s) {
    float a = fabsf(x) * s;
    unsigned int b;
    if      (a <= 0.25f) b = 0x00u;  // 0.0
    else if (a <= 0.75f) b = 0x30u;  // 0.5
    else if (a <= 1.25f) b = 0x38u;  // 1.0
    else if (a <= 1.75f) b = 0x3Cu;  // 1.5
    else if (a <= 2.5f)  b = 0x40u;  // 2.0
    else if (a <= 3.5f)  b = 0x44u;  // 3.0
    else if (a <= 5.0f)  b = 0x48u;  // 4.0
    else                 b = 0x4Cu;  // 6.0 (also handles clip)
    return b | ((__float_as_uint(x) >> 24) & 0x80u);
}
__device__ __forceinline__ unsigned int qpack4(float4 v, float s) {
    return q1(v.x, s) | (q1(v.y, s) << 8) | (q1(v.z, s) << 16) | (q1(v.w, s) << 24);
}

__global__ __launch_bounds__(256) void quant_kernel(
    const float4* __restrict__ x4, const float4* __restrict__ w4,
    float* __restrict__ ws_f, unsigned char* __restrict__ ws_b) {
    const int b = blockIdx.x, t = threadIdx.x;
    const bool is_x = b < 512;
    float m = 0.0f;
    if (is_x) {
        m = ws_f[PART_X_OFF + t];
    } else {
        for (int i = t; i < PART_W_N; i += 256)
            m = fmaxf(m, ws_f[PART_W_OFF + i]);
    }
    for (int off = 32; off > 0; off >>= 1)
        m = fmaxf(m, __shfl_down(m, off, 64));
    __shared__ float sm[4];
    if ((t & 63) == 0) sm[t >> 6] = m;
    __syncthreads();
    m = fmaxf(fmaxf(sm[0], sm[1]), fmaxf(sm[2], sm[3]));
    float amax = fmaxf(m, 1e-12f);
    float s = 6.0f / amax;
    if (t == 0 && b == 0)   ws_f[AMAX_OFF + 0] = amax;
    if (t == 0 && b == 512) ws_f[AMAX_OFF + 1] = amax;

    const float4* src = is_x ? x4 : w4;
    unsigned char* dstb = ws_b + (is_x ? XQ_BYTE_OFF : WQ_BYTE_OFF);
    const int idx16 = (is_x ? b : b - 512) * 256 + t;
    const float4* p = src + (size_t)idx16 * 4;
    uint4 o;
    o.x = qpack4(p[0], s);
    o.y = qpack4(p[1], s);
    o.z = qpack4(p[2], s);
    o.w = qpack4(p[3], s);
    ((uint4*)dstb)[idx16] = o;
}

// ----------------------------------------------------------------- GEMM -----
__device__ __forceinline__ void async_copy16(const void* g, void* l) {
    __builtin_amdgcn_global_load_lds(
        (const __attribute__((address_space(1))) unsigned int*)g,
        (__attribute__((address_space(3))) unsigned int*)l, 16, 0, 0);
}

// Load a 32B (K=32) fp8 fragment slice: two b128 reads from the XOR-swizzled
// aligned 16B-chunk pair {g0, g0+1} of one LDS row.
__device__ __forceinline__ i32x8 frag_load(const unsigned char* rowbase,
                                           int mask, int g0) {
    const i32x4 lo = *(const i32x4*)(rowbase + ((g0 ^ mask) * 16));
    const i32x4 hi = *(const i32x4*)(rowbase + (((g0 + 1) ^ mask) * 16));
    return __builtin_shufflevector(lo, hi, 0, 1, 2, 3, 4, 5, 6, 7);
}

// C[m,n] = sum_k A[m,k]*B[n,k], fp8 operands (codebook units), full K per
// block, plain stores. R6 structure (64x64 tile, 512 blocks = 2/CU, BK=512,
// 4 waves 2x2, XOR-swizzled LDS) but MFMA upgraded to the MX-scaled
// mfma_f32_16x16x128_f8f6f4 with unit scales (e8m0 0x7F = 1.0): 2x the
// non-scaled fp8 rate, identical LDS/L2 traffic, acc 64->16 VGPRs.
// Frag layout (16x16x128): lane l holds row l&15, k = (l>>4)*32 + 0..31
// (8 VGPRs, bytes low-to-high).
__global__ __launch_bounds__(256, 2) void gemm_kernel(
    const unsigned char* __restrict__ A, const unsigned char* __restrict__ B,
    float* __restrict__ C, const float* __restrict__ amax2) {
    __shared__ __align__(16) unsigned char As[64 * 512];
    __shared__ __align__(16) unsigned char Bs[64 * 512];

    const int bid  = blockIdx.x;
    // bid = mt*64 + g*8 + x : x = XCD slice (N), g = n-subtile, mt = m-tile
    const int bm   = (bid >> 6) * 64;
    const int bn   = ((bid & 7) * 8 + ((bid >> 3) & 7)) * 64;
    const int tid  = threadIdx.x;
    const int lane = tid & 63;
    const int wave = tid >> 6;
    const int wm   = (wave >> 1) * 32;
    const int wn   = (wave & 1) * 32;
    const int t15  = lane & 15;
    const int quad = lane >> 4;

    const float cs = (1.0f / (6.0f / fmaxf(amax2[0], 1e-12f))) *
                     (1.0f / (6.0f / fmaxf(amax2[1], 1e-12f)));

    // staging: chunk c = j*256 + tid, LDS byte c*16 (wave-uniform base +
    // lane*16). Physical slot (row=c>>5, pcol=c&31) holds global 16B-chunk
    // gk = pcol ^ (row&31) of that row.
    const unsigned char* agp[8];
    const unsigned char* bgp[8];
#pragma unroll
    for (int j = 0; j < 8; j++) {
        const int c = j * 256 + tid;
        const int row = c >> 5, pcol = c & 31;
        const int gk = pcol ^ (row & 31);
        agp[j] = A + (size_t)(bm + row) * K_DIM + gk * 16;
        bgp[j] = B + (size_t)(bn + row) * K_DIM + gk * 16;
    }

    f32x4 acc[2][2] = {};
    // fragment row bases; row&31 masks are {t15, t15+16} for wm,wn in {0,32}
    const unsigned char* A0 = As + (size_t)(wm + t15) * 512;
    const unsigned char* A1 = A0 + 16 * 512;
    const unsigned char* B0 = Bs + (size_t)(wn + t15) * 512;
    const unsigned char* B1 = B0 + 16 * 512;
    const int mk0 = t15, mk1 = t15 + 16;

    for (int ko = 0; ko < K_DIM; ko += 512) {
#pragma unroll
        for (int j = 0; j < 8; j++) {
            async_copy16(agp[j] + ko, As + (j * 256 + tid) * 16);
            async_copy16(bgp[j] + ko, Bs + (j * 256 + tid) * 16);
        }
        __syncthreads();

#pragma unroll
        for (int s = 0; s < 4; s++) {           // 4 x K=128 per stage
            const int g0 = s * 8 + (quad << 1); // even 16B-chunk index
            const i32x8 af0 = frag_load(A0, mk0, g0);
            const i32x8 af1 = frag_load(A1, mk1, g0);
            const i32x8 bf0 = frag_load(B0, mk0, g0);
            const i32x8 bf1 = frag_load(B1, mk1, g0);
            acc[0][0] = __builtin_amdgcn_mfma_scale_f32_16x16x128_f8f6f4(
                af0, bf0, acc[0][0], 0, 0, 0, 0x7F7F7F7F, 0, 0x7F7F7F7F);
            acc[0][1] = __builtin_amdgcn_mfma_scale_f32_16x16x128_f8f6f4(
                af0, bf1, acc[0][1], 0, 0, 0, 0x7F7F7F7F, 0, 0x7F7F7F7F);
            acc[1][0] = __builtin_amdgcn_mfma_scale_f32_16x16x128_f8f6f4(
                af1, bf0, acc[1][0], 0, 0, 0, 0x7F7F7F7F, 0, 0x7F7F7F7F);
            acc[1][1] = __builtin_amdgcn_mfma_scale_f32_16x16x128_f8f6f4(
                af1, bf1, acc[1][1], 0, 0, 0, 0x7F7F7F7F, 0, 0x7F7F7F7F);
        }
        __syncthreads();
    }

    // C/D layout (16x16): col = lane&15 (n), row = quad*4 + reg (m).
#pragma unroll
    for (int i = 0; i < 2; i++)
#pragma unroll
        for (int j = 0; j < 2; j++) {
            const int m0 = bm + wm + i * 16 + quad * 4;
            const int n0 = bn + wn + j * 16 + t15;
#pragma unroll
            for (int r = 0; r < 4; r++)
                C[(size_t)(m0 + r) * N_DIM + n0] = acc[i][j][r] * cs;
        }
}

// ---------------------------------------------------------------- launch ----
extern "C" void kernel_launch(void* const* d_in, const int* in_sizes, int n_in,
                              void* d_out, int out_size, void* d_ws, size_t ws_size,
                              hipStream_t stream) {
    const float* x = (const float*)d_in[0];   // [512, 4096]
    const float* w = (const float*)d_in[1];   // [4096, 4096]
    float* out = (float*)d_out;               // [512, 4096]

    float* ws_f = (float*)d_ws;
    unsigned char* ws_b = (unsigned char*)d_ws;
    const unsigned char* xq = ws_b + XQ_BYTE_OFF;
    const unsigned char* wq = ws_b + WQ_BYTE_OFF;

    amax_kernel<<<PART_X_N + PART_W_N, 256, 0, stream>>>(
        (const float4*)x, (const float4*)w, ws_f);
    quant_kernel<<<512 + 4096, 256, 0, stream>>>(
        (const float4*)x, (const float4*)w, ws_f, ws_b);
    gemm_kernel<<<(M_DIM / 64) * (N_DIM / 64), 256, 0, stream>>>(
        xq, wq, out, ws_f + AMAX_OFF);
}